// Round 8
// baseline (605.152 us; speedup 1.0000x reference)
//
#include <hip/hip_runtime.h>
#include <stdint.h>

typedef unsigned int u32;
typedef unsigned long long u64;
typedef _Float16 half8 __attribute__((ext_vector_type(8)));
typedef _Float16 half4 __attribute__((ext_vector_type(4)));
typedef float f32x4 __attribute__((ext_vector_type(4)));

#define M_TOT 32768
#define D_DIM 256
#define N_E   8192
#define BM 128
#define BN 256
#define SA 264
#define SB 40
// flag margin in RAW f16-acc units (validated PASS rounds 4/5/7/8/9/10)
#define MARGIN_RAW 0.16384f
// rescan candidate margin, RAW units (validated PASS rounds 7-10)
#define CAND_MARGIN2_RAW 0.35f
#define CBUF 2048

__device__ __forceinline__ u64 umax64(u64 a, u64 b) { return a > b ? a : b; }

__device__ __forceinline__ u32 map_f32(float f) {
    u32 u = __float_as_uint(f);
    return u ^ ((u32)((int)u >> 31) | 0x80000000u);
}

// ---- bitwise np-fp32 exact scoring of one (m,n) pair (validated r4-r10) ----
__device__ void exact_pair(const float* __restrict__ z, const float* __restrict__ emb,
                           int m, int n, u64* __restrict__ bg)
{
    #pragma clang fp contract(off)
    const float* zp = z + (long)m * D_DIM;
    const float* ep = emb + (long)n * D_DIM;
    float z2 = 0.0f;
    for (int h = 0; h < 2; ++h) {
        const float* p = zp + h * 128;
        float r0 = p[0]*p[0], r1 = p[1]*p[1], r2 = p[2]*p[2], r3 = p[3]*p[3];
        float r4 = p[4]*p[4], r5 = p[5]*p[5], r6 = p[6]*p[6], r7 = p[7]*p[7];
        for (int k = 8; k < 128; k += 8) {
            r0 += p[k+0]*p[k+0]; r1 += p[k+1]*p[k+1];
            r2 += p[k+2]*p[k+2]; r3 += p[k+3]*p[k+3];
            r4 += p[k+4]*p[k+4]; r5 += p[k+5]*p[k+5];
            r6 += p[k+6]*p[k+6]; r7 += p[k+7]*p[k+7];
        }
        z2 = z2 + (((r0 + r1) + (r2 + r3)) + ((r4 + r5) + (r6 + r7)));
    }
    float v0 = 0.f, v1 = 0.f, v2 = 0.f, v3 = 0.f;
    for (int it = 0; it < 16; ++it) {
        const float* zz = zp + it * 16;
        const float* ee = ep + it * 16;
        v0 = zz[0]*ee[0] + (zz[4]*ee[4] + (zz[8]*ee[8] + (zz[12]*ee[12] + v0)));
        v1 = zz[1]*ee[1] + (zz[5]*ee[5] + (zz[9]*ee[9] + (zz[13]*ee[13] + v1)));
        v2 = zz[2]*ee[2] + (zz[6]*ee[6] + (zz[10]*ee[10] + (zz[14]*ee[14] + v2)));
        v3 = zz[3]*ee[3] + (zz[7]*ee[7] + (zz[11]*ee[11] + (zz[15]*ee[15] + v3)));
    }
    float dot = (v0 + v1) + (v2 + v3);
    float q = z2 - 2.0f * dot;
    atomicMin(&bg[m], ((u64)map_f32(q) << 32) | (u64)(u32)n);
}

// ---------------- setup: init counters + emb -> f16 scaled x8192 ------------
__global__ void k_setup(const float* __restrict__ emb, _Float16* __restrict__ emb_h,
                        int* counts, int* amb_cnt, double* accum, u64* bg) {
    long i = (long)blockIdx.x * 1024 + threadIdx.x * 4;
    float4 v = *(const float4*)(emb + i);
    half4 h = { (_Float16)(v.x * 8192.0f), (_Float16)(v.y * 8192.0f),
                (_Float16)(v.z * 8192.0f), (_Float16)(v.w * 8192.0f) };
    *(half4*)(emb_h + i) = h;

    int gid = blockIdx.x * 256 + threadIdx.x;
    if (gid < M_TOT) bg[gid] = ~0ull;
    if (gid < N_E) counts[gid] = 0;
    if (gid == 0) { *amb_cnt = 0; *accum = 0.0; }
}

// ---------------- f16 MFMA screen v14: r7 schedule, register cap fixed ------
// r7's spill (WRITE 103 MB) was the (512,2) launch-bounds VGPR cap of 128
// (pool 512/SIMD / 4 declared waves), not the schedule: afl 64 + acc 64 +
// bfA/bfB 64 + temps ~ 217 regs. __launch_bounds__(512) (no waves arg) only
// enforces launchability (8-wave block -> cap 256) -> fits, no spill, same
// occupancy (LDS 128 KB caps at 1 block/CU regardless; 2x~220 < 512 pool).
// Schedule (r7, correctness-validated): rotate bfA/bfB register buffers so
// every MFMA cluster starts with operands resident:
//   vmcnt(4); barrier; SB0; stage(s+3); ds_read bfB(s,kk1);
//   MFMA kk0 (pre-loaded bfA); ds_read bfA(s+1,kk0) from buf s+1;
//   MFMA kk1 (bfB).
__global__ __launch_bounds__(512) void k_argmax(
    const float* __restrict__ z, const _Float16* __restrict__ emb_h,
    int* __restrict__ idx_int,
    int* __restrict__ amb_list, int* __restrict__ amb_cnt, float* __restrict__ smax)
{
    __shared__ _Float16 smem[4 * 16384];   // 4 x 32KB Bs ring = 131072 B

    const int t = threadIdx.x;
    const int w = t >> 6;           // 8 waves
    const int wrow = w >> 1;        // 4 row-groups of 32 rows
    const int wcol = w & 1;         // 2 col-slices of 128
    const int lane = t & 63;
    const int quad = lane >> 4;
    const int l15 = lane & 15;
    const int m0 = blockIdx.x * BM;
    const int wn = wcol * 128;

    // Bs staging (r5/r6-validated): thread t stages 4x16B; row n=(t>>3)+i*64;
    // source k-granule pre-swizzled (t&7)^(n&7) -> linear dest = swizzled LDS.
    const int nbase = t >> 3;
    const int kgr = (t & 7) ^ (nbase & 7);

    auto stage = [&](int s) {   // s in [0,128): nt = s>>2, kb = s&3; buf s&3
        const int nt2 = s >> 2, kb2 = s & 3;
        const _Float16* gb = emb_h + (long)nt2 * (BN * D_DIM) + kb2 * 64 + kgr * 8;
        _Float16* lbase = smem + (s & 3) * 16384 + t * 8;
        #pragma unroll
        for (int i = 0; i < 4; ++i) {
            __builtin_amdgcn_global_load_lds(
                (const __attribute__((address_space(1))) u32*)(gb + (long)(nbase + i * 64) * D_DIM),
                (__attribute__((address_space(3))) u32*)(lbase + i * 4096), 16, 0, 0);
        }
    };

    // swizzled bf read: buffer byte base + row n, k-half kk
    auto bfread = [&](int bufoff, int n, int kk) -> half8 {
        return *(const half8*)((const char*)smem + bufoff +
                (n << 7) + (((kk << 6) + (quad << 4)) ^ ((n & 7) << 4)));
    };

    // ---- prologue: z tile -> swizzled As (ring region), lift A to regs ----
    #pragma unroll
    for (int i = 0; i < 16; ++i) {
        int c = i * 512 + t;
        int row = c >> 6, q4 = c & 63;
        float4 v = *(const float4*)&z[(long)(m0 + row) * D_DIM + q4 * 4];
        half4 h = { (_Float16)v.x, (_Float16)v.y, (_Float16)v.z, (_Float16)v.w };
        *(half4*)((char*)smem + (((row << 9) + (q4 << 3)) ^ ((row & 7) << 4))) = h;
    }
    __syncthreads();

    half8 afl[2][8];
    #pragma unroll
    for (int mi = 0; mi < 2; ++mi) {
        #pragma unroll
        for (int ks = 0; ks < 8; ++ks) {
            const int row = wrow * 32 + mi * 16 + l15;
            afl[mi][ks] = *(const half8*)((const char*)smem +
                    (((row << 9) + (ks << 6) + (quad << 4)) ^ ((row & 7) << 4)));
        }
    }
    __syncthreads();          // all afl reads done before ring DMA overwrites
    stage(0); stage(1); stage(2);
    // drain stage(0): 12 outstanding -> 8; barrier; preload bfA(0, kk=0)
    asm volatile("s_waitcnt vmcnt(8)" ::: "memory");
    __builtin_amdgcn_s_barrier();

    half8 bfA[8];
    #pragma unroll
    for (int ni = 0; ni < 8; ++ni)
        bfA[ni] = bfread(0, wn + ni * 16 + l15, 0);

    float f1[8], f2[8];
    u32 pay[8];
    #pragma unroll
    for (int g = 0; g < 8; ++g) { f1[g] = -3.0e38f; f2[g] = -3.0e38f; pay[g] = 0u; }

    for (int nt = 0; nt < N_E / BN; ++nt) {
        f32x4 acc[2][8];
        #pragma unroll
        for (int mi = 0; mi < 2; ++mi)
            #pragma unroll
            for (int ni = 0; ni < 8; ++ni)
                acc[mi][ni] = (f32x4){0.f, 0.f, 0.f, 0.f};

        #pragma unroll
        for (int kb = 0; kb < 4; ++kb) {
            const int s = nt * 4 + kb;
            // bufs s and s+1 guaranteed landed after this (see invariant)
            asm volatile("s_waitcnt vmcnt(4)" ::: "memory");
            __builtin_amdgcn_s_barrier();
            __builtin_amdgcn_sched_barrier(0);
            stage((s + 3) & 127);
            const int bufoff  = (s & 3) * 32768;        // bytes
            const int bufoff1 = ((s + 1) & 3) * 32768;  // bytes

            // read kk=1 of current buf (lands under MFMA kk0)
            half8 bfB[8];
            #pragma unroll
            for (int ni = 0; ni < 8; ++ni)
                bfB[ni] = bfread(bufoff, wn + ni * 16 + l15, 1);

            // MFMA kk=0 with pre-loaded bfA
            __builtin_amdgcn_s_setprio(1);
            #pragma unroll
            for (int mi = 0; mi < 2; ++mi)
                #pragma unroll
                for (int ni = 0; ni < 8; ++ni)
                    acc[mi][ni] = __builtin_amdgcn_mfma_f32_16x16x32_f16(
                        afl[mi][kb * 2 + 0], bfA[ni], acc[mi][ni], 0, 0, 0);
            __builtin_amdgcn_s_setprio(0);

            // read next step's kk=0 from buf s+1 (dead-but-harmless at s=127)
            #pragma unroll
            for (int ni = 0; ni < 8; ++ni)
                bfA[ni] = bfread(bufoff1, wn + ni * 16 + l15, 0);

            // MFMA kk=1 with bfB
            __builtin_amdgcn_s_setprio(1);
            #pragma unroll
            for (int mi = 0; mi < 2; ++mi)
                #pragma unroll
                for (int ni = 0; ni < 8; ++ni)
                    acc[mi][ni] = __builtin_amdgcn_mfma_f32_16x16x32_f16(
                        afl[mi][kb * 2 + 1], bfB[ni], acc[mi][ni], 0, 0, 0);
            __builtin_amdgcn_s_setprio(0);
        }

        const u32 pbase = (u32)(nt << 3);
        #pragma unroll
        for (int mi = 0; mi < 2; ++mi) {
            #pragma unroll
            for (int reg = 0; reg < 4; ++reg) {
                const int g = mi * 4 + reg;
                float s0 = acc[mi][0][reg], s1 = acc[mi][1][reg];
                float s2 = acc[mi][2][reg], s3 = acc[mi][3][reg];
                float s4 = acc[mi][4][reg], s5 = acc[mi][5][reg];
                float s6 = acc[mi][6][reg], s7 = acc[mi][7][reg];
                float h01 = fmaxf(s0, s1), l01 = fminf(s0, s1);
                float h23 = fmaxf(s2, s3), l23 = fminf(s2, s3);
                float h45 = fmaxf(s4, s5), l45 = fminf(s4, s5);
                float h67 = fmaxf(s6, s7), l67 = fminf(s6, s7);
                u32 j01 = (s1 > s0) ? 1u : 0u;
                u32 j23 = (s3 > s2) ? 3u : 2u;
                u32 j45 = (s5 > s4) ? 5u : 4u;
                u32 j67 = (s7 > s6) ? 7u : 6u;
                float hA = fmaxf(h01, h23);
                float sA = fmaxf(fminf(h01, h23), fmaxf(l01, l23));
                u32 jA = (h23 > h01) ? j23 : j01;
                float hB = fmaxf(h45, h67);
                float sB = fmaxf(fminf(h45, h67), fmaxf(l45, l67));
                u32 jB = (h67 > h45) ? j67 : j45;
                float m8 = fmaxf(hA, hB);
                float sec8 = fmaxf(fminf(hA, hB), fmaxf(sA, sB));
                u32 j8 = (hB > hA) ? jB : jA;
                bool rec = m8 > f1[g];
                f2[g] = fmaxf(f2[g], fmaxf(sec8, fminf(f1[g], m8)));
                f1[g] = fmaxf(f1[g], m8);
                pay[g] = rec ? (pbase | j8) : pay[g];
            }
        }
    }

    // drain in-flight dummy stages + sync, then alias reduction arrays
    __syncthreads();
    u64* redB1   = (u64*)smem;                      // [8][32]  2048 B
    float* redF1 = (float*)((char*)smem + 2048);    // [8][32]  1024 B
    float* redF2 = (float*)((char*)smem + 3072);    // [8][32]  1024 B

    #pragma unroll
    for (int g = 0; g < 8; ++g) {
        u32 nt_ = pay[g] >> 3, j_ = pay[g] & 7u;
        u32 n = nt_ * 256 + (u32)wn + j_ * 16 + (u32)l15;
        u64 B = ((u64)map_f32(f1[g]) << 32) | (u64)(8191u - n);
        float F1 = f1[g], F2 = f2[g];
        #pragma unroll
        for (int o = 1; o < 16; o <<= 1) {
            float oF1 = __shfl_xor(F1, o, 64);
            float oF2 = __shfl_xor(F2, o, 64);
            u64 oB = __shfl_xor(B, o, 64);
            F2 = fmaxf(fmaxf(F2, oF2), fminf(F1, oF1));
            F1 = fmaxf(F1, oF1);
            B = umax64(B, oB);
        }
        if (l15 == 0) {
            int mi = g >> 2, reg = g & 3;
            int r = mi * 16 + quad * 4 + reg;        // local row in [0,32)
            redB1[w * 32 + r] = B;
            redF1[w * 32 + r] = F1;
            redF2[w * 32 + r] = F2;
        }
    }
    __syncthreads();
    if (t < BM) {
        const int wr = t >> 5;                       // row-group of this row
        const int r  = t & 31;
        u64 B = 0ull; float F1 = -3.0e38f, F2 = -3.0e38f;
        #pragma unroll
        for (int wc = 0; wc < 2; ++wc) {
            int wi = wr * 2 + wc;
            u64 v = redB1[wi * 32 + r];
            float nf1 = redF1[wi * 32 + r], nf2 = redF2[wi * 32 + r];
            F2 = fmaxf(fmaxf(F2, nf2), fminf(F1, nf1));
            F1 = fmaxf(F1, nf1);
            B = umax64(B, v);
        }
        int m = m0 + t;
        idx_int[m] = 8191 - (int)(B & 0xFFFFFFFFu);
        smax[m] = F1;
        if (F1 - F2 < MARGIN_RAW) {
            int p = atomicAdd(amb_cnt, 1);
            if (p < M_TOT) amb_list[p] = m;
        }
    }
}

// ---------------- rescan of flagged rows + inline exact (r10, validated) ----
__global__ __launch_bounds__(256, 2) void k_cand(
    const float* __restrict__ z, const float* __restrict__ emb,
    const _Float16* __restrict__ emb_h, const float* __restrict__ smax,
    const int* __restrict__ amb_list, const int* __restrict__ amb_cnt,
    u64* __restrict__ bg)
{
    __shared__ _Float16 As[64 * SA];
    __shared__ _Float16 Bs[BN * SB];
    __shared__ int ml[64];
    __shared__ float thr_s[64];
    __shared__ u32 cbuf[CBUF];
    __shared__ int ccnt;

    int cnt = *amb_cnt; if (cnt > M_TOT) cnt = M_TOT;
    const int ngroups = (cnt + 63) >> 6;
    const int nunits = ngroups * 8;
    const int t = threadIdx.x;
    const int w = t >> 6, lane = t & 63, quad = lane >> 4, l15 = lane & 15;
    const int wn = w * 64;
    if (t == 0) ccnt = 0;

    for (int u = blockIdx.x; u < nunits; u += gridDim.x) {
        const int g = u >> 3, slice = u & 7;
        __syncthreads();
        if (t < 64) {
            int gi = g * 64 + t;
            int mm = amb_list[gi < cnt ? gi : cnt - 1];
            ml[t] = mm;
            thr_s[t] = smax[mm] - CAND_MARGIN2_RAW;
        }
        __syncthreads();
        #pragma unroll
        for (int i = 0; i < 16; ++i) {
            int c = i * 256 + t;
            int row = c >> 6, q = c & 63;
            float4 v = *(const float4*)&z[(long)ml[row] * D_DIM + q * 4];
            half4 h = { (_Float16)v.x, (_Float16)v.y, (_Float16)v.z, (_Float16)v.w };
            *(half4*)&As[row * SA + q * 4] = h;
        }
        __syncthreads();

        for (int st = 0; st < 4; ++st) {
            const int n0 = slice * 1024 + st * 256;
            f32x4 acc[4][4];
            #pragma unroll
            for (int mi = 0; mi < 4; ++mi)
                #pragma unroll
                for (int ni = 0; ni < 4; ++ni)
                    acc[mi][ni] = (f32x4){0.f, 0.f, 0.f, 0.f};

            for (int ks = 0; ks < 8; ++ks) {
                __syncthreads();
                #pragma unroll
                for (int i = 0; i < 4; ++i) {
                    int c = i * 256 + t;
                    int col = c >> 2, seg = c & 3;
                    *(half8*)&Bs[col * SB + seg * 8] =
                        *(const half8*)&emb_h[(long)(n0 + col) * D_DIM + ks * 32 + seg * 8];
                }
                __syncthreads();
                half8 af[4], bf[4];
                #pragma unroll
                for (int mi = 0; mi < 4; ++mi)
                    af[mi] = *(const half8*)&As[(mi * 16 + l15) * SA + ks * 32 + quad * 8];
                #pragma unroll
                for (int ni = 0; ni < 4; ++ni)
                    bf[ni] = *(const half8*)&Bs[(wn + ni * 16 + l15) * SB + quad * 8];
                #pragma unroll
                for (int mi = 0; mi < 4; ++mi)
                    #pragma unroll
                    for (int ni = 0; ni < 4; ++ni)
                        acc[mi][ni] = __builtin_amdgcn_mfma_f32_16x16x32_f16(af[mi], bf[ni], acc[mi][ni], 0, 0, 0);
            }

            #pragma unroll
            for (int mi = 0; mi < 4; ++mi) {
                #pragma unroll
                for (int reg = 0; reg < 4; ++reg) {
                    int r = mi * 16 + quad * 4 + reg;
                    float th = thr_s[r];
                    u32 mm = (u32)ml[r];
                    #pragma unroll
                    for (int ni = 0; ni < 4; ++ni) {
                        if (acc[mi][ni][reg] >= th) {
                            u32 n = (u32)(n0 + wn + ni * 16 + l15);
                            int p = atomicAdd(&ccnt, 1);
                            if (p < CBUF) cbuf[p] = (mm << 13) | n;
                            else exact_pair(z, emb, (int)mm, (int)n, bg);
                        }
                    }
                }
            }
        }

        __syncthreads();
        int nc = ccnt; if (nc > CBUF) nc = CBUF;
        for (int j = t; j < nc; j += 256) {
            u32 cd = cbuf[j];
            exact_pair(z, emb, (int)(cd >> 13), (int)(cd & 8191u), bg);
        }
        __syncthreads();
        if (t == 0) ccnt = 0;
    }
}

// ---------------- z_q gather + losses accum + histogram + idx publish -------
__global__ void k_out(const float* __restrict__ z, const float* __restrict__ emb,
                      const int* __restrict__ idx_int, const u64* __restrict__ bg,
                      float* __restrict__ zq, float* __restrict__ out_idx_f,
                      double* __restrict__ accum, int* __restrict__ counts)
{
    int gid = blockIdx.x * 256 + threadIdx.x;
    if (gid < M_TOT) {
        u64 b = bg[gid];
        int ic = (b != ~0ull) ? (int)(b & 8191u) : idx_int[gid];
        out_idx_f[gid] = (float)ic;
        atomicAdd(&counts[ic], 1);
    }

    long base = (long)blockIdx.x * 1024 + threadIdx.x * 4;
    int m = (int)(base >> 8), d = (int)(base & 255);
    u64 bm = bg[m];
    int idxm = (bm != ~0ull) ? (int)(bm & 8191u) : idx_int[m];
    float4 ev = *(const float4*)&emb[(long)idxm * D_DIM + d];
    float4 zv = *(const float4*)&z[base];
    *(float4*)&zq[base] = ev;
    float dx = ev.x - zv.x, dy = ev.y - zv.y, dz = ev.z - zv.z, dw = ev.w - zv.w;
    float s = dx * dx + dy * dy + dz * dz + dw * dw;
    for (int o = 32; o > 0; o >>= 1) s += __shfl_down(s, o, 64);
    __shared__ float red[4];
    if ((threadIdx.x & 63) == 0) red[threadIdx.x >> 6] = s;
    __syncthreads();
    if (threadIdx.x == 0) atomicAdd(accum, (double)(red[0] + red[1] + red[2] + red[3]));
}

// ---------------- losses + code stats (r9, validated) -----------------------
__global__ void k_final(const float* __restrict__ code_age, const float* __restrict__ code_usage,
                        const int* __restrict__ counts, const double* __restrict__ accum,
                        float* __restrict__ out_losses, float* __restrict__ out_age,
                        float* __restrict__ out_usage)
{
    int n = blockIdx.x * 256 + threadIdx.x;
    if (n < N_E) {
        int c = counts[n];
        out_age[n] = (c > 0) ? 0.0f : code_age[n] + 1.0f;
        out_usage[n] = code_usage[n] + (float)c;
    }
    if (n == 0) {
        double mean = *accum / (double)((long)M_TOT * D_DIM);
        out_losses[0] = (float)(0.25 * mean);
        out_losses[1] = (float)mean;
    }
}

extern "C" void kernel_launch(void* const* d_in, const int* in_sizes, int n_in,
                              void* d_out, int out_size, void* d_ws, size_t ws_size,
                              hipStream_t stream) {
    const float* z          = (const float*)d_in[0];
    const float* emb        = (const float*)d_in[1];
    const float* code_age   = (const float*)d_in[2];
    const float* code_usage = (const float*)d_in[3];

    float* out        = (float*)d_out;
    float* out_zq     = out;                       // 8388608
    float* out_losses = out + 8388608;             // 2
    float* out_idx    = out + 8388610;             // 32768
    float* out_age    = out + 8388610 + M_TOT;     // 8192
    float* out_usage  = out_age + N_E;             // 8192

    char* ws = (char*)d_ws;
    _Float16* emb_h = (_Float16*)(ws);             // 4 MB
    int* idx_int    = (int*)(ws + 4194304);        // 128 KB
    int* counts     = (int*)(ws + 4325376);        // 32 KB
    int* amb_list   = (int*)(ws + 4358144);        // 128 KB
    int* amb_cnt    = (int*)(ws + 4489216);        // 8
    double* accum   = (double*)(ws + 4489224);     // 8
    u64* bg         = (u64*)(ws + 4489232);        // 256 KB
    float* smax     = (float*)(ws + 4751376);      // 128 KB

    k_setup<<<2048, 256, 0, stream>>>(emb, emb_h, counts, amb_cnt, accum, bg);
    k_argmax<<<M_TOT / BM, 512, 0, stream>>>(z, emb_h, idx_int,
                                             amb_list, amb_cnt, smax);
    k_cand<<<512, 256, 0, stream>>>(z, emb, emb_h, smax, amb_list, amb_cnt, bg);
    k_out<<<8192, 256, 0, stream>>>(z, emb, idx_int, bg, out_zq, out_idx,
                                    accum, counts);
    k_final<<<32, 256, 0, stream>>>(code_age, code_usage, counts, accum,
                                    out_losses, out_age, out_usage);
}

// Round 9
// 513.796 us; speedup vs baseline: 1.1778x; 1.1778x over previous
//
#include <hip/hip_runtime.h>
#include <stdint.h>

typedef unsigned int u32;
typedef unsigned long long u64;
typedef _Float16 half8 __attribute__((ext_vector_type(8)));
typedef _Float16 half4 __attribute__((ext_vector_type(4)));
typedef float f32x4 __attribute__((ext_vector_type(4)));

#define M_TOT 32768
#define D_DIM 256
#define N_E   8192
#define BM 128
#define BN 256
#define SA 264
#define SB 40
// flag margin in RAW f16-acc units (validated PASS rounds 4/5/7/8/9/10)
#define MARGIN_RAW 0.16384f
// rescan candidate margin, RAW units (validated PASS rounds 7-10)
#define CAND_MARGIN2_RAW 0.35f
#define CBUF 2048

__device__ __forceinline__ u64 umax64(u64 a, u64 b) { return a > b ? a : b; }

__device__ __forceinline__ u32 map_f32(float f) {
    u32 u = __float_as_uint(f);
    return u ^ ((u32)((int)u >> 31) | 0x80000000u);
}

// ---- bitwise np-fp32 exact scoring of one (m,n) pair (validated r4-r10) ----
__device__ void exact_pair(const float* __restrict__ z, const float* __restrict__ emb,
                           int m, int n, u64* __restrict__ bg)
{
    #pragma clang fp contract(off)
    const float* zp = z + (long)m * D_DIM;
    const float* ep = emb + (long)n * D_DIM;
    float z2 = 0.0f;
    for (int h = 0; h < 2; ++h) {
        const float* p = zp + h * 128;
        float r0 = p[0]*p[0], r1 = p[1]*p[1], r2 = p[2]*p[2], r3 = p[3]*p[3];
        float r4 = p[4]*p[4], r5 = p[5]*p[5], r6 = p[6]*p[6], r7 = p[7]*p[7];
        for (int k = 8; k < 128; k += 8) {
            r0 += p[k+0]*p[k+0]; r1 += p[k+1]*p[k+1];
            r2 += p[k+2]*p[k+2]; r3 += p[k+3]*p[k+3];
            r4 += p[k+4]*p[k+4]; r5 += p[k+5]*p[k+5];
            r6 += p[k+6]*p[k+6]; r7 += p[k+7]*p[k+7];
        }
        z2 = z2 + (((r0 + r1) + (r2 + r3)) + ((r4 + r5) + (r6 + r7)));
    }
    float v0 = 0.f, v1 = 0.f, v2 = 0.f, v3 = 0.f;
    for (int it = 0; it < 16; ++it) {
        const float* zz = zp + it * 16;
        const float* ee = ep + it * 16;
        v0 = zz[0]*ee[0] + (zz[4]*ee[4] + (zz[8]*ee[8] + (zz[12]*ee[12] + v0)));
        v1 = zz[1]*ee[1] + (zz[5]*ee[5] + (zz[9]*ee[9] + (zz[13]*ee[13] + v1)));
        v2 = zz[2]*ee[2] + (zz[6]*ee[6] + (zz[10]*ee[10] + (zz[14]*ee[14] + v2)));
        v3 = zz[3]*ee[3] + (zz[7]*ee[7] + (zz[11]*ee[11] + (zz[15]*ee[15] + v3)));
    }
    float dot = (v0 + v1) + (v2 + v3);
    float q = z2 - 2.0f * dot;
    atomicMin(&bg[m], ((u64)map_f32(q) << 32) | (u64)(u32)n);
}

// ---------------- setup: init counters + emb -> f16 scaled x8192 ------------
__global__ void k_setup(const float* __restrict__ emb, _Float16* __restrict__ emb_h,
                        int* counts, int* amb_cnt, u64* bg) {
    long i = (long)blockIdx.x * 1024 + threadIdx.x * 4;
    float4 v = *(const float4*)(emb + i);
    half4 h = { (_Float16)(v.x * 8192.0f), (_Float16)(v.y * 8192.0f),
                (_Float16)(v.z * 8192.0f), (_Float16)(v.w * 8192.0f) };
    *(half4*)(emb_h + i) = h;

    int gid = blockIdx.x * 256 + threadIdx.x;
    if (gid < M_TOT) bg[gid] = ~0ull;
    if (gid < N_E) counts[gid] = 0;
    if (gid == 0) *amb_cnt = 0;
}

// ---------------- f16 MFMA screen v15: r7 schedule, TRUE 256-reg cap --------
// Empirical launch-bounds law on this toolchain: VGPR cap = 256/waves_arg
// (r2: (256,3)->84~=256/3; r7: (512,2)->128=256/2; r8: no-arg -> heuristic
// 128). (512,1) -> cap 256: fits the ~217-reg working set (afl 64 + acc 64 +
// bfA/bfB 64 + temps), 2 waves x ~220 = 440 < 512 pool/SIMD, occupancy
// unchanged (LDS 128KB caps at 1 block/CU). Schedule = r7 (validated twice
// for correctness, never yet run unspilled): rotate bfA/bfB so every MFMA
// cluster starts with operands resident.
__global__ __launch_bounds__(512, 1) void k_argmax(
    const float* __restrict__ z, const _Float16* __restrict__ emb_h,
    int* __restrict__ idx_int,
    int* __restrict__ amb_list, int* __restrict__ amb_cnt, float* __restrict__ smax)
{
    __shared__ _Float16 smem[4 * 16384];   // 4 x 32KB Bs ring = 131072 B

    const int t = threadIdx.x;
    const int w = t >> 6;           // 8 waves
    const int wrow = w >> 1;        // 4 row-groups of 32 rows
    const int wcol = w & 1;         // 2 col-slices of 128
    const int lane = t & 63;
    const int quad = lane >> 4;
    const int l15 = lane & 15;
    const int m0 = blockIdx.x * BM;
    const int wn = wcol * 128;

    // Bs staging (r5/r6-validated): thread t stages 4x16B; row n=(t>>3)+i*64;
    // source k-granule pre-swizzled (t&7)^(n&7) -> linear dest = swizzled LDS.
    const int nbase = t >> 3;
    const int kgr = (t & 7) ^ (nbase & 7);

    auto stage = [&](int s) {   // s in [0,128): nt = s>>2, kb = s&3; buf s&3
        const int nt2 = s >> 2, kb2 = s & 3;
        const _Float16* gb = emb_h + (long)nt2 * (BN * D_DIM) + kb2 * 64 + kgr * 8;
        _Float16* lbase = smem + (s & 3) * 16384 + t * 8;
        #pragma unroll
        for (int i = 0; i < 4; ++i) {
            __builtin_amdgcn_global_load_lds(
                (const __attribute__((address_space(1))) u32*)(gb + (long)(nbase + i * 64) * D_DIM),
                (__attribute__((address_space(3))) u32*)(lbase + i * 4096), 16, 0, 0);
        }
    };

    // swizzled bf read: buffer byte base + row n, k-half kk
    auto bfread = [&](int bufoff, int n, int kk) -> half8 {
        return *(const half8*)((const char*)smem + bufoff +
                (n << 7) + (((kk << 6) + (quad << 4)) ^ ((n & 7) << 4)));
    };

    // ---- prologue: z tile -> swizzled As (ring region), lift A to regs ----
    #pragma unroll
    for (int i = 0; i < 16; ++i) {
        int c = i * 512 + t;
        int row = c >> 6, q4 = c & 63;
        float4 v = *(const float4*)&z[(long)(m0 + row) * D_DIM + q4 * 4];
        half4 h = { (_Float16)v.x, (_Float16)v.y, (_Float16)v.z, (_Float16)v.w };
        *(half4*)((char*)smem + (((row << 9) + (q4 << 3)) ^ ((row & 7) << 4))) = h;
    }
    __syncthreads();

    half8 afl[2][8];
    #pragma unroll
    for (int mi = 0; mi < 2; ++mi) {
        #pragma unroll
        for (int ks = 0; ks < 8; ++ks) {
            const int row = wrow * 32 + mi * 16 + l15;
            afl[mi][ks] = *(const half8*)((const char*)smem +
                    (((row << 9) + (ks << 6) + (quad << 4)) ^ ((row & 7) << 4)));
        }
    }
    __syncthreads();          // all afl reads done before ring DMA overwrites
    stage(0); stage(1); stage(2);
    // drain stage(0): 12 outstanding -> 8; barrier; preload bfA(0, kk=0)
    asm volatile("s_waitcnt vmcnt(8)" ::: "memory");
    __builtin_amdgcn_s_barrier();

    half8 bfA[8];
    #pragma unroll
    for (int ni = 0; ni < 8; ++ni)
        bfA[ni] = bfread(0, wn + ni * 16 + l15, 0);

    float f1[8], f2[8];
    u32 pay[8];
    #pragma unroll
    for (int g = 0; g < 8; ++g) { f1[g] = -3.0e38f; f2[g] = -3.0e38f; pay[g] = 0u; }

    for (int nt = 0; nt < N_E / BN; ++nt) {
        f32x4 acc[2][8];
        #pragma unroll
        for (int mi = 0; mi < 2; ++mi)
            #pragma unroll
            for (int ni = 0; ni < 8; ++ni)
                acc[mi][ni] = (f32x4){0.f, 0.f, 0.f, 0.f};

        #pragma unroll
        for (int kb = 0; kb < 4; ++kb) {
            const int s = nt * 4 + kb;
            // bufs s and s+1 guaranteed landed after this (see invariant)
            asm volatile("s_waitcnt vmcnt(4)" ::: "memory");
            __builtin_amdgcn_s_barrier();
            __builtin_amdgcn_sched_barrier(0);
            stage((s + 3) & 127);
            const int bufoff  = (s & 3) * 32768;        // bytes
            const int bufoff1 = ((s + 1) & 3) * 32768;  // bytes

            // read kk=1 of current buf (lands under MFMA kk0)
            half8 bfB[8];
            #pragma unroll
            for (int ni = 0; ni < 8; ++ni)
                bfB[ni] = bfread(bufoff, wn + ni * 16 + l15, 1);

            // MFMA kk=0 with pre-loaded bfA
            __builtin_amdgcn_s_setprio(1);
            #pragma unroll
            for (int mi = 0; mi < 2; ++mi)
                #pragma unroll
                for (int ni = 0; ni < 8; ++ni)
                    acc[mi][ni] = __builtin_amdgcn_mfma_f32_16x16x32_f16(
                        afl[mi][kb * 2 + 0], bfA[ni], acc[mi][ni], 0, 0, 0);
            __builtin_amdgcn_s_setprio(0);

            // read next step's kk=0 from buf s+1 (dead-but-harmless at s=127)
            #pragma unroll
            for (int ni = 0; ni < 8; ++ni)
                bfA[ni] = bfread(bufoff1, wn + ni * 16 + l15, 0);

            // MFMA kk=1 with bfB
            __builtin_amdgcn_s_setprio(1);
            #pragma unroll
            for (int mi = 0; mi < 2; ++mi)
                #pragma unroll
                for (int ni = 0; ni < 8; ++ni)
                    acc[mi][ni] = __builtin_amdgcn_mfma_f32_16x16x32_f16(
                        afl[mi][kb * 2 + 1], bfB[ni], acc[mi][ni], 0, 0, 0);
            __builtin_amdgcn_s_setprio(0);
        }

        const u32 pbase = (u32)(nt << 3);
        #pragma unroll
        for (int mi = 0; mi < 2; ++mi) {
            #pragma unroll
            for (int reg = 0; reg < 4; ++reg) {
                const int g = mi * 4 + reg;
                float s0 = acc[mi][0][reg], s1 = acc[mi][1][reg];
                float s2 = acc[mi][2][reg], s3 = acc[mi][3][reg];
                float s4 = acc[mi][4][reg], s5 = acc[mi][5][reg];
                float s6 = acc[mi][6][reg], s7 = acc[mi][7][reg];
                float h01 = fmaxf(s0, s1), l01 = fminf(s0, s1);
                float h23 = fmaxf(s2, s3), l23 = fminf(s2, s3);
                float h45 = fmaxf(s4, s5), l45 = fminf(s4, s5);
                float h67 = fmaxf(s6, s7), l67 = fminf(s6, s7);
                u32 j01 = (s1 > s0) ? 1u : 0u;
                u32 j23 = (s3 > s2) ? 3u : 2u;
                u32 j45 = (s5 > s4) ? 5u : 4u;
                u32 j67 = (s7 > s6) ? 7u : 6u;
                float hA = fmaxf(h01, h23);
                float sA = fmaxf(fminf(h01, h23), fmaxf(l01, l23));
                u32 jA = (h23 > h01) ? j23 : j01;
                float hB = fmaxf(h45, h67);
                float sB = fmaxf(fminf(h45, h67), fmaxf(l45, l67));
                u32 jB = (h67 > h45) ? j67 : j45;
                float m8 = fmaxf(hA, hB);
                float sec8 = fmaxf(fminf(hA, hB), fmaxf(sA, sB));
                u32 j8 = (hB > hA) ? jB : jA;
                bool rec = m8 > f1[g];
                f2[g] = fmaxf(f2[g], fmaxf(sec8, fminf(f1[g], m8)));
                f1[g] = fmaxf(f1[g], m8);
                pay[g] = rec ? (pbase | j8) : pay[g];
            }
        }
    }

    // drain in-flight dummy stages + sync, then alias reduction arrays
    __syncthreads();
    u64* redB1   = (u64*)smem;                      // [8][32]  2048 B
    float* redF1 = (float*)((char*)smem + 2048);    // [8][32]  1024 B
    float* redF2 = (float*)((char*)smem + 3072);    // [8][32]  1024 B

    #pragma unroll
    for (int g = 0; g < 8; ++g) {
        u32 nt_ = pay[g] >> 3, j_ = pay[g] & 7u;
        u32 n = nt_ * 256 + (u32)wn + j_ * 16 + (u32)l15;
        u64 B = ((u64)map_f32(f1[g]) << 32) | (u64)(8191u - n);
        float F1 = f1[g], F2 = f2[g];
        #pragma unroll
        for (int o = 1; o < 16; o <<= 1) {
            float oF1 = __shfl_xor(F1, o, 64);
            float oF2 = __shfl_xor(F2, o, 64);
            u64 oB = __shfl_xor(B, o, 64);
            F2 = fmaxf(fmaxf(F2, oF2), fminf(F1, oF1));
            F1 = fmaxf(F1, oF1);
            B = umax64(B, oB);
        }
        if (l15 == 0) {
            int mi = g >> 2, reg = g & 3;
            int r = mi * 16 + quad * 4 + reg;        // local row in [0,32)
            redB1[w * 32 + r] = B;
            redF1[w * 32 + r] = F1;
            redF2[w * 32 + r] = F2;
        }
    }
    __syncthreads();
    if (t < BM) {
        const int wr = t >> 5;                       // row-group of this row
        const int r  = t & 31;
        u64 B = 0ull; float F1 = -3.0e38f, F2 = -3.0e38f;
        #pragma unroll
        for (int wc = 0; wc < 2; ++wc) {
            int wi = wr * 2 + wc;
            u64 v = redB1[wi * 32 + r];
            float nf1 = redF1[wi * 32 + r], nf2 = redF2[wi * 32 + r];
            F2 = fmaxf(fmaxf(F2, nf2), fminf(F1, nf1));
            F1 = fmaxf(F1, nf1);
            B = umax64(B, v);
        }
        int m = m0 + t;
        idx_int[m] = 8191 - (int)(B & 0xFFFFFFFFu);
        smax[m] = F1;
        if (F1 - F2 < MARGIN_RAW) {
            int p = atomicAdd(amb_cnt, 1);
            if (p < M_TOT) amb_list[p] = m;
        }
    }
}

// ---------------- rescan of flagged rows + inline exact (r10, validated) ----
__global__ __launch_bounds__(256, 2) void k_cand(
    const float* __restrict__ z, const float* __restrict__ emb,
    const _Float16* __restrict__ emb_h, const float* __restrict__ smax,
    const int* __restrict__ amb_list, const int* __restrict__ amb_cnt,
    u64* __restrict__ bg)
{
    __shared__ _Float16 As[64 * SA];
    __shared__ _Float16 Bs[BN * SB];
    __shared__ int ml[64];
    __shared__ float thr_s[64];
    __shared__ u32 cbuf[CBUF];
    __shared__ int ccnt;

    int cnt = *amb_cnt; if (cnt > M_TOT) cnt = M_TOT;
    const int ngroups = (cnt + 63) >> 6;
    const int nunits = ngroups * 8;
    const int t = threadIdx.x;
    const int w = t >> 6, lane = t & 63, quad = lane >> 4, l15 = lane & 15;
    const int wn = w * 64;
    if (t == 0) ccnt = 0;

    for (int u = blockIdx.x; u < nunits; u += gridDim.x) {
        const int g = u >> 3, slice = u & 7;
        __syncthreads();
        if (t < 64) {
            int gi = g * 64 + t;
            int mm = amb_list[gi < cnt ? gi : cnt - 1];
            ml[t] = mm;
            thr_s[t] = smax[mm] - CAND_MARGIN2_RAW;
        }
        __syncthreads();
        #pragma unroll
        for (int i = 0; i < 16; ++i) {
            int c = i * 256 + t;
            int row = c >> 6, q = c & 63;
            float4 v = *(const float4*)&z[(long)ml[row] * D_DIM + q * 4];
            half4 h = { (_Float16)v.x, (_Float16)v.y, (_Float16)v.z, (_Float16)v.w };
            *(half4*)&As[row * SA + q * 4] = h;
        }
        __syncthreads();

        for (int st = 0; st < 4; ++st) {
            const int n0 = slice * 1024 + st * 256;
            f32x4 acc[4][4];
            #pragma unroll
            for (int mi = 0; mi < 4; ++mi)
                #pragma unroll
                for (int ni = 0; ni < 4; ++ni)
                    acc[mi][ni] = (f32x4){0.f, 0.f, 0.f, 0.f};

            for (int ks = 0; ks < 8; ++ks) {
                __syncthreads();
                #pragma unroll
                for (int i = 0; i < 4; ++i) {
                    int c = i * 256 + t;
                    int col = c >> 2, seg = c & 3;
                    *(half8*)&Bs[col * SB + seg * 8] =
                        *(const half8*)&emb_h[(long)(n0 + col) * D_DIM + ks * 32 + seg * 8];
                }
                __syncthreads();
                half8 af[4], bf[4];
                #pragma unroll
                for (int mi = 0; mi < 4; ++mi)
                    af[mi] = *(const half8*)&As[(mi * 16 + l15) * SA + ks * 32 + quad * 8];
                #pragma unroll
                for (int ni = 0; ni < 4; ++ni)
                    bf[ni] = *(const half8*)&Bs[(wn + ni * 16 + l15) * SB + quad * 8];
                #pragma unroll
                for (int mi = 0; mi < 4; ++mi)
                    #pragma unroll
                    for (int ni = 0; ni < 4; ++ni)
                        acc[mi][ni] = __builtin_amdgcn_mfma_f32_16x16x32_f16(af[mi], bf[ni], acc[mi][ni], 0, 0, 0);
            }

            #pragma unroll
            for (int mi = 0; mi < 4; ++mi) {
                #pragma unroll
                for (int reg = 0; reg < 4; ++reg) {
                    int r = mi * 16 + quad * 4 + reg;
                    float th = thr_s[r];
                    u32 mm = (u32)ml[r];
                    #pragma unroll
                    for (int ni = 0; ni < 4; ++ni) {
                        if (acc[mi][ni][reg] >= th) {
                            u32 n = (u32)(n0 + wn + ni * 16 + l15);
                            int p = atomicAdd(&ccnt, 1);
                            if (p < CBUF) cbuf[p] = (mm << 13) | n;
                            else exact_pair(z, emb, (int)mm, (int)n, bg);
                        }
                    }
                }
            }
        }

        __syncthreads();
        int nc = ccnt; if (nc > CBUF) nc = CBUF;
        for (int j = t; j < nc; j += 256) {
            u32 cd = cbuf[j];
            exact_pair(z, emb, (int)(cd >> 13), (int)(cd & 8191u), bg);
        }
        __syncthreads();
        if (t == 0) ccnt = 0;
    }
}

// ---------------- z_q gather + losses + histogram, per-block partials -------
// grid 1024 x 256, x8 work/thread. The former single-address atomicAdd(double)
// (8192 serialized f64 atomics -> suspected ~100+ us tail) is replaced by
// accum_part[block]; k_final reduces. Numerics: f32 per-thread/block sums as
// before, stored as double partials; deterministic tree in k_final.
__global__ __launch_bounds__(256) void k_out(
    const float* __restrict__ z, const float* __restrict__ emb,
    const int* __restrict__ idx_int, const u64* __restrict__ bg,
    float* __restrict__ zq, float* __restrict__ out_idx_f,
    double* __restrict__ accum_part, int* __restrict__ counts)
{
    const int b = blockIdx.x, t = threadIdx.x;
    int gid = b * 256 + t;
    if (gid < M_TOT) {
        u64 bv = bg[gid];
        int ic = (bv != ~0ull) ? (int)(bv & 8191u) : idx_int[gid];
        out_idx_f[gid] = (float)ic;
        atomicAdd(&counts[ic], 1);
    }

    float s = 0.f;
    #pragma unroll
    for (int i = 0; i < 8; ++i) {
        long base = ((long)(b * 8 + i) * 256 + t) * 4;
        int m = (int)(base >> 8), d = (int)(base & 255);
        u64 bm = bg[m];
        int idxm = (bm != ~0ull) ? (int)(bm & 8191u) : idx_int[m];
        float4 ev = *(const float4*)&emb[(long)idxm * D_DIM + d];
        float4 zv = *(const float4*)&z[base];
        *(float4*)&zq[base] = ev;
        float dx = ev.x - zv.x, dy = ev.y - zv.y;
        float dz2 = ev.z - zv.z, dw = ev.w - zv.w;
        s += dx * dx + dy * dy + dz2 * dz2 + dw * dw;
    }
    for (int o = 32; o > 0; o >>= 1) s += __shfl_down(s, o, 64);
    __shared__ float red[4];
    if ((t & 63) == 0) red[t >> 6] = s;
    __syncthreads();
    if (t == 0) accum_part[b] = (double)(red[0] + red[1] + red[2] + red[3]);
}

// ---------------- losses + code stats; block 0 reduces the partials ---------
__global__ void k_final(const float* __restrict__ code_age, const float* __restrict__ code_usage,
                        const int* __restrict__ counts, const double* __restrict__ accum_part,
                        float* __restrict__ out_losses, float* __restrict__ out_age,
                        float* __restrict__ out_usage)
{
    int n = blockIdx.x * 256 + threadIdx.x;
    if (n < N_E) {
        int c = counts[n];
        out_age[n] = (c > 0) ? 0.0f : code_age[n] + 1.0f;
        out_usage[n] = code_usage[n] + (float)c;
    }
    if (blockIdx.x == 0) {
        const int t = threadIdx.x;
        __shared__ double dred[256];
        dred[t] = accum_part[t] + accum_part[t + 256]
                + accum_part[t + 512] + accum_part[t + 768];
        __syncthreads();
        for (int o = 128; o > 0; o >>= 1) {
            if (t < o) dred[t] += dred[t + o];
            __syncthreads();
        }
        if (t == 0) {
            double mean = dred[0] / (double)((long)M_TOT * D_DIM);
            out_losses[0] = (float)(0.25 * mean);
            out_losses[1] = (float)mean;
        }
    }
}

extern "C" void kernel_launch(void* const* d_in, const int* in_sizes, int n_in,
                              void* d_out, int out_size, void* d_ws, size_t ws_size,
                              hipStream_t stream) {
    const float* z          = (const float*)d_in[0];
    const float* emb        = (const float*)d_in[1];
    const float* code_age   = (const float*)d_in[2];
    const float* code_usage = (const float*)d_in[3];

    float* out        = (float*)d_out;
    float* out_zq     = out;                       // 8388608
    float* out_losses = out + 8388608;             // 2
    float* out_idx    = out + 8388610;             // 32768
    float* out_age    = out + 8388610 + M_TOT;     // 8192
    float* out_usage  = out_age + N_E;             // 8192

    char* ws = (char*)d_ws;
    _Float16* emb_h = (_Float16*)(ws);             // 4 MB
    int* idx_int    = (int*)(ws + 4194304);        // 128 KB
    int* counts     = (int*)(ws + 4325376);        // 32 KB
    int* amb_list   = (int*)(ws + 4358144);        // 128 KB
    int* amb_cnt    = (int*)(ws + 4489216);        // 8
    u64* bg         = (u64*)(ws + 4489232);        // 256 KB
    float* smax     = (float*)(ws + 4751376);      // 128 KB
    double* accum_part = (double*)(ws + 4882448);  // 8 KB (1024 doubles)

    k_setup<<<2048, 256, 0, stream>>>(emb, emb_h, counts, amb_cnt, bg);
    k_argmax<<<M_TOT / BM, 512, 0, stream>>>(z, emb_h, idx_int,
                                             amb_list, amb_cnt, smax);
    k_cand<<<512, 256, 0, stream>>>(z, emb, emb_h, smax, amb_list, amb_cnt, bg);
    k_out<<<1024, 256, 0, stream>>>(z, emb, idx_int, bg, out_zq, out_idx,
                                    accum_part, counts);
    k_final<<<32, 256, 0, stream>>>(code_age, code_usage, counts, accum_part,
                                    out_losses, out_age, out_usage);
}

// Round 10
// 338.821 us; speedup vs baseline: 1.7860x; 1.5164x over previous
//
#include <hip/hip_runtime.h>
#include <stdint.h>

typedef unsigned int u32;
typedef unsigned long long u64;
typedef _Float16 half8 __attribute__((ext_vector_type(8)));
typedef _Float16 half4 __attribute__((ext_vector_type(4)));
typedef float f32x4 __attribute__((ext_vector_type(4)));

#define M_TOT 32768
#define D_DIM 256
#define N_E   8192
#define BM 128
#define BN 256
#define SA 264
#define SB 40
// flag margin in RAW f16-acc units (validated PASS rounds 4/5/7/8/9/10)
#define MARGIN_RAW 0.16384f
// rescan candidate margin, RAW units (validated PASS rounds 7-10)
#define CAND_MARGIN2_RAW 0.35f
#define CBUF 2048

__device__ __forceinline__ u64 umax64(u64 a, u64 b) { return a > b ? a : b; }

__device__ __forceinline__ u32 map_f32(float f) {
    u32 u = __float_as_uint(f);
    return u ^ ((u32)((int)u >> 31) | 0x80000000u);
}

// ---- bitwise np-fp32 exact scoring of one (m,n) pair (validated r4-r10) ----
__device__ void exact_pair(const float* __restrict__ z, const float* __restrict__ emb,
                           int m, int n, u64* __restrict__ bg)
{
    #pragma clang fp contract(off)
    const float* zp = z + (long)m * D_DIM;
    const float* ep = emb + (long)n * D_DIM;
    float z2 = 0.0f;
    for (int h = 0; h < 2; ++h) {
        const float* p = zp + h * 128;
        float r0 = p[0]*p[0], r1 = p[1]*p[1], r2 = p[2]*p[2], r3 = p[3]*p[3];
        float r4 = p[4]*p[4], r5 = p[5]*p[5], r6 = p[6]*p[6], r7 = p[7]*p[7];
        for (int k = 8; k < 128; k += 8) {
            r0 += p[k+0]*p[k+0]; r1 += p[k+1]*p[k+1];
            r2 += p[k+2]*p[k+2]; r3 += p[k+3]*p[k+3];
            r4 += p[k+4]*p[k+4]; r5 += p[k+5]*p[k+5];
            r6 += p[k+6]*p[k+6]; r7 += p[k+7]*p[k+7];
        }
        z2 = z2 + (((r0 + r1) + (r2 + r3)) + ((r4 + r5) + (r6 + r7)));
    }
    float v0 = 0.f, v1 = 0.f, v2 = 0.f, v3 = 0.f;
    for (int it = 0; it < 16; ++it) {
        const float* zz = zp + it * 16;
        const float* ee = ep + it * 16;
        v0 = zz[0]*ee[0] + (zz[4]*ee[4] + (zz[8]*ee[8] + (zz[12]*ee[12] + v0)));
        v1 = zz[1]*ee[1] + (zz[5]*ee[5] + (zz[9]*ee[9] + (zz[13]*ee[13] + v1)));
        v2 = zz[2]*ee[2] + (zz[6]*ee[6] + (zz[10]*ee[10] + (zz[14]*ee[14] + v2)));
        v3 = zz[3]*ee[3] + (zz[7]*ee[7] + (zz[11]*ee[11] + (zz[15]*ee[15] + v3)));
    }
    float dot = (v0 + v1) + (v2 + v3);
    float q = z2 - 2.0f * dot;
    atomicMin(&bg[m], ((u64)map_f32(q) << 32) | (u64)(u32)n);
}

// ---------------- setup: init counters + emb -> f16 scaled x8192 ------------
__global__ void k_setup(const float* __restrict__ emb, _Float16* __restrict__ emb_h,
                        int* counts, int* amb_cnt, u64* bg) {
    long i = (long)blockIdx.x * 1024 + threadIdx.x * 4;
    float4 v = *(const float4*)(emb + i);
    half4 h = { (_Float16)(v.x * 8192.0f), (_Float16)(v.y * 8192.0f),
                (_Float16)(v.z * 8192.0f), (_Float16)(v.w * 8192.0f) };
    *(half4*)(emb_h + i) = h;

    int gid = blockIdx.x * 256 + threadIdx.x;
    if (gid < M_TOT) bg[gid] = ~0ull;
    if (gid < N_E) counts[gid] = 0;
    if (gid == 0) *amb_cnt = 0;
}

// ---------------- f16 MFMA screen v16 = r6 verbatim (consolidation) ---------
// Evidence r7/r8/r9: 512-thread blocks are hard-capped at 128 VGPR on this
// toolchain regardless of launch-bounds args; the ~217-reg cross-step bf
// rotation ALWAYS spills (WRITE 103 MB, 2x slower). r6's variant fills the
// 128-reg cap exactly (afl 64 + acc 64) with bf read in-step: 176 us, no
// spill, validated. This is the argmax structure ceiling at this block shape.
__global__ __launch_bounds__(512, 2) void k_argmax(
    const float* __restrict__ z, const _Float16* __restrict__ emb_h,
    int* __restrict__ idx_int,
    int* __restrict__ amb_list, int* __restrict__ amb_cnt, float* __restrict__ smax)
{
    __shared__ _Float16 smem[4 * 16384];   // 4 x 32KB Bs ring = 131072 B

    const int t = threadIdx.x;
    const int w = t >> 6;           // 8 waves
    const int wrow = w >> 1;        // 4 row-groups of 32 rows
    const int wcol = w & 1;         // 2 col-slices of 128
    const int lane = t & 63;
    const int quad = lane >> 4;
    const int l15 = lane & 15;
    const int m0 = blockIdx.x * BM;
    const int wn = wcol * 128;

    // Bs staging: thread t stages 4x16B; row n = (t>>3)+i*64; source k-granule
    // pre-swizzled (t&7)^(n&7) so linear LDS dest = XOR-swizzled layout (r5).
    const int nbase = t >> 3;
    const int kgr = (t & 7) ^ (nbase & 7);

    auto stage = [&](int s) {   // s in [0,128): nt = s>>2, kb = s&3; buf s&3
        const int nt2 = s >> 2, kb2 = s & 3;
        const _Float16* gb = emb_h + (long)nt2 * (BN * D_DIM) + kb2 * 64 + kgr * 8;
        _Float16* lbase = smem + (s & 3) * 16384 + t * 8;
        #pragma unroll
        for (int i = 0; i < 4; ++i) {
            __builtin_amdgcn_global_load_lds(
                (const __attribute__((address_space(1))) u32*)(gb + (long)(nbase + i * 64) * D_DIM),
                (__attribute__((address_space(3))) u32*)(lbase + i * 4096), 16, 0, 0);
        }
    };

    // ---- prologue: z tile -> swizzled As (ring bufs 0-1 region), then lift
    // all 16 A-fragments into registers; As region dies, ring starts ----
    #pragma unroll
    for (int i = 0; i < 16; ++i) {
        int c = i * 512 + t;
        int row = c >> 6, q4 = c & 63;
        float4 v = *(const float4*)&z[(long)(m0 + row) * D_DIM + q4 * 4];
        half4 h = { (_Float16)v.x, (_Float16)v.y, (_Float16)v.z, (_Float16)v.w };
        *(half4*)((char*)smem + (((row << 9) + (q4 << 3)) ^ ((row & 7) << 4))) = h;
    }
    __syncthreads();

    half8 afl[2][8];
    #pragma unroll
    for (int mi = 0; mi < 2; ++mi) {
        #pragma unroll
        for (int ks = 0; ks < 8; ++ks) {
            const int row = wrow * 32 + mi * 16 + l15;
            afl[mi][ks] = *(const half8*)((const char*)smem +
                    (((row << 9) + (ks << 6) + (quad << 4)) ^ ((row & 7) << 4)));
        }
    }
    __syncthreads();          // all afl reads done before ring DMA overwrites
    stage(0); stage(1); stage(2);

    float f1[8], f2[8];
    u32 pay[8];
    #pragma unroll
    for (int g = 0; g < 8; ++g) { f1[g] = -3.0e38f; f2[g] = -3.0e38f; pay[g] = 0u; }

    for (int nt = 0; nt < N_E / BN; ++nt) {
        f32x4 acc[2][8];
        #pragma unroll
        for (int mi = 0; mi < 2; ++mi)
            #pragma unroll
            for (int ni = 0; ni < 8; ++ni)
                acc[mi][ni] = (f32x4){0.f, 0.f, 0.f, 0.f};

        #pragma unroll
        for (int kb = 0; kb < 4; ++kb) {
            const int s = nt * 4 + kb;
            // wait for stage(s) only (3 stages in flight = 12 loads; keep 8)
            asm volatile("s_waitcnt vmcnt(8)" ::: "memory");
            __builtin_amdgcn_s_barrier();
            __builtin_amdgcn_sched_barrier(0);
            // prefetch depth-3; tail wraps into dead buffers (r1-validated)
            stage((s + 3) & 127);
            const int bufoff = (s & 3) * 32768;   // bytes
            #pragma unroll
            for (int kk = 0; kk < 2; ++kk) {
                half8 bf[8];
                #pragma unroll
                for (int ni = 0; ni < 8; ++ni) {
                    const int n = wn + ni * 16 + l15;
                    bf[ni] = *(const half8*)((const char*)smem + bufoff +
                            (n << 7) + (((kk << 6) + (quad << 4)) ^ ((n & 7) << 4)));
                }
                __builtin_amdgcn_s_setprio(1);
                #pragma unroll
                for (int mi = 0; mi < 2; ++mi)
                    #pragma unroll
                    for (int ni = 0; ni < 8; ++ni)
                        acc[mi][ni] = __builtin_amdgcn_mfma_f32_16x16x32_f16(
                            afl[mi][kb * 2 + kk], bf[ni], acc[mi][ni], 0, 0, 0);
                __builtin_amdgcn_s_setprio(0);
            }
        }

        const u32 pbase = (u32)(nt << 3);
        #pragma unroll
        for (int mi = 0; mi < 2; ++mi) {
            #pragma unroll
            for (int reg = 0; reg < 4; ++reg) {
                const int g = mi * 4 + reg;
                float s0 = acc[mi][0][reg], s1 = acc[mi][1][reg];
                float s2 = acc[mi][2][reg], s3 = acc[mi][3][reg];
                float s4 = acc[mi][4][reg], s5 = acc[mi][5][reg];
                float s6 = acc[mi][6][reg], s7 = acc[mi][7][reg];
                float h01 = fmaxf(s0, s1), l01 = fminf(s0, s1);
                float h23 = fmaxf(s2, s3), l23 = fminf(s2, s3);
                float h45 = fmaxf(s4, s5), l45 = fminf(s4, s5);
                float h67 = fmaxf(s6, s7), l67 = fminf(s6, s7);
                u32 j01 = (s1 > s0) ? 1u : 0u;
                u32 j23 = (s3 > s2) ? 3u : 2u;
                u32 j45 = (s5 > s4) ? 5u : 4u;
                u32 j67 = (s7 > s6) ? 7u : 6u;
                float hA = fmaxf(h01, h23);
                float sA = fmaxf(fminf(h01, h23), fmaxf(l01, l23));
                u32 jA = (h23 > h01) ? j23 : j01;
                float hB = fmaxf(h45, h67);
                float sB = fmaxf(fminf(h45, h67), fmaxf(l45, l67));
                u32 jB = (h67 > h45) ? j67 : j45;
                float m8 = fmaxf(hA, hB);
                float sec8 = fmaxf(fminf(hA, hB), fmaxf(sA, sB));
                u32 j8 = (hB > hA) ? jB : jA;
                bool rec = m8 > f1[g];
                f2[g] = fmaxf(f2[g], fmaxf(sec8, fminf(f1[g], m8)));
                f1[g] = fmaxf(f1[g], m8);
                pay[g] = rec ? (pbase | j8) : pay[g];
            }
        }
    }

    // drain in-flight dummy stages + sync, then alias reduction arrays
    __syncthreads();
    u64* redB1   = (u64*)smem;                      // [8][32]  2048 B
    float* redF1 = (float*)((char*)smem + 2048);    // [8][32]  1024 B
    float* redF2 = (float*)((char*)smem + 3072);    // [8][32]  1024 B

    #pragma unroll
    for (int g = 0; g < 8; ++g) {
        u32 nt_ = pay[g] >> 3, j_ = pay[g] & 7u;
        u32 n = nt_ * 256 + (u32)wn + j_ * 16 + (u32)l15;
        u64 B = ((u64)map_f32(f1[g]) << 32) | (u64)(8191u - n);
        float F1 = f1[g], F2 = f2[g];
        #pragma unroll
        for (int o = 1; o < 16; o <<= 1) {
            float oF1 = __shfl_xor(F1, o, 64);
            float oF2 = __shfl_xor(F2, o, 64);
            u64 oB = __shfl_xor(B, o, 64);
            F2 = fmaxf(fmaxf(F2, oF2), fminf(F1, oF1));
            F1 = fmaxf(F1, oF1);
            B = umax64(B, oB);
        }
        if (l15 == 0) {
            int mi = g >> 2, reg = g & 3;
            int r = mi * 16 + quad * 4 + reg;        // local row in [0,32)
            redB1[w * 32 + r] = B;
            redF1[w * 32 + r] = F1;
            redF2[w * 32 + r] = F2;
        }
    }
    __syncthreads();
    if (t < BM) {
        const int wr = t >> 5;                       // row-group of this row
        const int r  = t & 31;
        u64 B = 0ull; float F1 = -3.0e38f, F2 = -3.0e38f;
        #pragma unroll
        for (int wc = 0; wc < 2; ++wc) {
            int wi = wr * 2 + wc;
            u64 v = redB1[wi * 32 + r];
            float nf1 = redF1[wi * 32 + r], nf2 = redF2[wi * 32 + r];
            F2 = fmaxf(fmaxf(F2, nf2), fminf(F1, nf1));
            F1 = fmaxf(F1, nf1);
            B = umax64(B, v);
        }
        int m = m0 + t;
        idx_int[m] = 8191 - (int)(B & 0xFFFFFFFFu);
        smax[m] = F1;
        if (F1 - F2 < MARGIN_RAW) {
            int p = atomicAdd(amb_cnt, 1);
            if (p < M_TOT) amb_list[p] = m;
        }
    }
}

// ---------------- rescan of flagged rows + inline exact (r10, validated) ----
__global__ __launch_bounds__(256, 2) void k_cand(
    const float* __restrict__ z, const float* __restrict__ emb,
    const _Float16* __restrict__ emb_h, const float* __restrict__ smax,
    const int* __restrict__ amb_list, const int* __restrict__ amb_cnt,
    u64* __restrict__ bg)
{
    __shared__ _Float16 As[64 * SA];
    __shared__ _Float16 Bs[BN * SB];
    __shared__ int ml[64];
    __shared__ float thr_s[64];
    __shared__ u32 cbuf[CBUF];
    __shared__ int ccnt;

    int cnt = *amb_cnt; if (cnt > M_TOT) cnt = M_TOT;
    const int ngroups = (cnt + 63) >> 6;
    const int nunits = ngroups * 8;
    const int t = threadIdx.x;
    const int w = t >> 6, lane = t & 63, quad = lane >> 4, l15 = lane & 15;
    const int wn = w * 64;
    if (t == 0) ccnt = 0;

    for (int u = blockIdx.x; u < nunits; u += gridDim.x) {
        const int g = u >> 3, slice = u & 7;
        __syncthreads();
        if (t < 64) {
            int gi = g * 64 + t;
            int mm = amb_list[gi < cnt ? gi : cnt - 1];
            ml[t] = mm;
            thr_s[t] = smax[mm] - CAND_MARGIN2_RAW;
        }
        __syncthreads();
        #pragma unroll
        for (int i = 0; i < 16; ++i) {
            int c = i * 256 + t;
            int row = c >> 6, q = c & 63;
            float4 v = *(const float4*)&z[(long)ml[row] * D_DIM + q * 4];
            half4 h = { (_Float16)v.x, (_Float16)v.y, (_Float16)v.z, (_Float16)v.w };
            *(half4*)&As[row * SA + q * 4] = h;
        }
        __syncthreads();

        for (int st = 0; st < 4; ++st) {
            const int n0 = slice * 1024 + st * 256;
            f32x4 acc[4][4];
            #pragma unroll
            for (int mi = 0; mi < 4; ++mi)
                #pragma unroll
                for (int ni = 0; ni < 4; ++ni)
                    acc[mi][ni] = (f32x4){0.f, 0.f, 0.f, 0.f};

            for (int ks = 0; ks < 8; ++ks) {
                __syncthreads();
                #pragma unroll
                for (int i = 0; i < 4; ++i) {
                    int c = i * 256 + t;
                    int col = c >> 2, seg = c & 3;
                    *(half8*)&Bs[col * SB + seg * 8] =
                        *(const half8*)&emb_h[(long)(n0 + col) * D_DIM + ks * 32 + seg * 8];
                }
                __syncthreads();
                half8 af[4], bf[4];
                #pragma unroll
                for (int mi = 0; mi < 4; ++mi)
                    af[mi] = *(const half8*)&As[(mi * 16 + l15) * SA + ks * 32 + quad * 8];
                #pragma unroll
                for (int ni = 0; ni < 4; ++ni)
                    bf[ni] = *(const half8*)&Bs[(wn + ni * 16 + l15) * SB + quad * 8];
                #pragma unroll
                for (int mi = 0; mi < 4; ++mi)
                    #pragma unroll
                    for (int ni = 0; ni < 4; ++ni)
                        acc[mi][ni] = __builtin_amdgcn_mfma_f32_16x16x32_f16(af[mi], bf[ni], acc[mi][ni], 0, 0, 0);
            }

            #pragma unroll
            for (int mi = 0; mi < 4; ++mi) {
                #pragma unroll
                for (int reg = 0; reg < 4; ++reg) {
                    int r = mi * 16 + quad * 4 + reg;
                    float th = thr_s[r];
                    u32 mm = (u32)ml[r];
                    #pragma unroll
                    for (int ni = 0; ni < 4; ++ni) {
                        if (acc[mi][ni][reg] >= th) {
                            u32 n = (u32)(n0 + wn + ni * 16 + l15);
                            int p = atomicAdd(&ccnt, 1);
                            if (p < CBUF) cbuf[p] = (mm << 13) | n;
                            else exact_pair(z, emb, (int)mm, (int)n, bg);
                        }
                    }
                }
            }
        }

        __syncthreads();
        int nc = ccnt; if (nc > CBUF) nc = CBUF;
        for (int j = t; j < nc; j += 256) {
            u32 cd = cbuf[j];
            exact_pair(z, emb, (int)(cd >> 13), (int)(cd & 8191u), bg);
        }
        __syncthreads();
        if (t == 0) ccnt = 0;
    }
}

// ---------------- z_q gather + losses + histogram, per-block partials -------
// (r9-validated; replaced the single-address f64 atomic tail: -88 us)
__global__ __launch_bounds__(256) void k_out(
    const float* __restrict__ z, const float* __restrict__ emb,
    const int* __restrict__ idx_int, const u64* __restrict__ bg,
    float* __restrict__ zq, float* __restrict__ out_idx_f,
    double* __restrict__ accum_part, int* __restrict__ counts)
{
    const int b = blockIdx.x, t = threadIdx.x;
    int gid = b * 256 + t;
    if (gid < M_TOT) {
        u64 bv = bg[gid];
        int ic = (bv != ~0ull) ? (int)(bv & 8191u) : idx_int[gid];
        out_idx_f[gid] = (float)ic;
        atomicAdd(&counts[ic], 1);
    }

    float s = 0.f;
    #pragma unroll
    for (int i = 0; i < 8; ++i) {
        long base = ((long)(b * 8 + i) * 256 + t) * 4;
        int m = (int)(base >> 8), d = (int)(base & 255);
        u64 bm = bg[m];
        int idxm = (bm != ~0ull) ? (int)(bm & 8191u) : idx_int[m];
        float4 ev = *(const float4*)&emb[(long)idxm * D_DIM + d];
        float4 zv = *(const float4*)&z[base];
        *(float4*)&zq[base] = ev;
        float dx = ev.x - zv.x, dy = ev.y - zv.y;
        float dz2 = ev.z - zv.z, dw = ev.w - zv.w;
        s += dx * dx + dy * dy + dz2 * dz2 + dw * dw;
    }
    for (int o = 32; o > 0; o >>= 1) s += __shfl_down(s, o, 64);
    __shared__ float red[4];
    if ((t & 63) == 0) red[t >> 6] = s;
    __syncthreads();
    if (t == 0) accum_part[b] = (double)(red[0] + red[1] + red[2] + red[3]);
}

// ---------------- losses + code stats; block 0 reduces the partials ---------
__global__ void k_final(const float* __restrict__ code_age, const float* __restrict__ code_usage,
                        const int* __restrict__ counts, const double* __restrict__ accum_part,
                        float* __restrict__ out_losses, float* __restrict__ out_age,
                        float* __restrict__ out_usage)
{
    int n = blockIdx.x * 256 + threadIdx.x;
    if (n < N_E) {
        int c = counts[n];
        out_age[n] = (c > 0) ? 0.0f : code_age[n] + 1.0f;
        out_usage[n] = code_usage[n] + (float)c;
    }
    if (blockIdx.x == 0) {
        const int t = threadIdx.x;
        __shared__ double dred[256];
        dred[t] = accum_part[t] + accum_part[t + 256]
                + accum_part[t + 512] + accum_part[t + 768];
        __syncthreads();
        for (int o = 128; o > 0; o >>= 1) {
            if (t < o) dred[t] += dred[t + o];
            __syncthreads();
        }
        if (t == 0) {
            double mean = dred[0] / (double)((long)M_TOT * D_DIM);
            out_losses[0] = (float)(0.25 * mean);
            out_losses[1] = (float)mean;
        }
    }
}

extern "C" void kernel_launch(void* const* d_in, const int* in_sizes, int n_in,
                              void* d_out, int out_size, void* d_ws, size_t ws_size,
                              hipStream_t stream) {
    const float* z          = (const float*)d_in[0];
    const float* emb        = (const float*)d_in[1];
    const float* code_age   = (const float*)d_in[2];
    const float* code_usage = (const float*)d_in[3];

    float* out        = (float*)d_out;
    float* out_zq     = out;                       // 8388608
    float* out_losses = out + 8388608;             // 2
    float* out_idx    = out + 8388610;             // 32768
    float* out_age    = out + 8388610 + M_TOT;     // 8192
    float* out_usage  = out_age + N_E;             // 8192

    char* ws = (char*)d_ws;
    _Float16* emb_h = (_Float16*)(ws);             // 4 MB
    int* idx_int    = (int*)(ws + 4194304);        // 128 KB
    int* counts     = (int*)(ws + 4325376);        // 32 KB
    int* amb_list   = (int*)(ws + 4358144);        // 128 KB
    int* amb_cnt    = (int*)(ws + 4489216);        // 8
    u64* bg         = (u64*)(ws + 4489232);        // 256 KB
    float* smax     = (float*)(ws + 4751376);      // 128 KB
    double* accum_part = (double*)(ws + 4882448);  // 8 KB (1024 doubles)

    k_setup<<<2048, 256, 0, stream>>>(emb, emb_h, counts, amb_cnt, bg);
    k_argmax<<<M_TOT / BM, 512, 0, stream>>>(z, emb_h, idx_int,
                                             amb_list, amb_cnt, smax);
    k_cand<<<512, 256, 0, stream>>>(z, emb, emb_h, smax, amb_list, amb_cnt, bg);
    k_out<<<1024, 256, 0, stream>>>(z, emb, idx_int, bg, out_zq, out_idx,
                                    accum_part, counts);
    k_final<<<32, 256, 0, stream>>>(code_age, code_usage, counts, accum_part,
                                    out_losses, out_age, out_usage);
}